// Round 3
// baseline (81.846 us; speedup 1.0000x reference)
//
#include <hip/hip_runtime.h>

// SKANLinear: y[b,o] = sum_{i=0}^{IN} weight[o,i] * sin(w[o,i] * x_ext[b,i])
// x_ext[b,IN] = 1.0. B=2048, IN=256, OUT=256. f32.
//
// R2 post-mortem: v_sin fix moved nothing -> kernel is VMEM-line-bound
// (weight rows are 1028B-strided = 64B-misaligned, 8 lines/instr; x float4
// loads carry 4x og-duplication). R3: stage weight/w/x tiles into LDS with
// coalesced float4 staging (~11 VMEM instrs/wave), compute from LDS.
// Weight LDS stride 257 (odd) -> 2-way bank aliasing = free (m136).
// x LDS reads are ds_read_b128 with og-broadcast = free.
// w is pre-scaled by 1/2pi at staging time (v_sin_f32 takes revolutions).
//
// Wave layout: lane = 16*og_in_wave + iq; og = wave*4 + (lane>>4) picks the
// o-row, iq picks a 4-float i-quad. shfl_xor(1,2,4,8) reduces iq lanes.

#define IN_DIM 256
#define OUT_DIM 256
#define LDW 257      // row stride = IN+1 (kept odd in LDS: bank-friendly)
#define BTILE 8      // batches per block
#define OTILE 16     // o-rows per block (4 waves x 4 og)

#define INV_2PI 0.15915494309189535f

__global__ __launch_bounds__(256, 3)
void skan_kernel(const float* __restrict__ x,      // [B][256]
                 const float* __restrict__ weight, // [256][257]
                 const float* __restrict__ wfreq,  // [256][257]
                 float* __restrict__ y)            // [B][256]
{
    __shared__ float lw[OTILE * LDW];  // wfreq * INV_2PI, 16 rows
    __shared__ float lg[OTILE * LDW];  // weight, 16 rows
    __shared__ float lx[BTILE * IN_DIM];

    const int t    = threadIdx.x;
    const int lane = t & 63;
    const int wave = t >> 6;
    const int iq   = lane & 15;
    const int og   = wave * 4 + (lane >> 4);

    const int obase = (blockIdx.x & 15) * OTILE;
    const int b0    = (blockIdx.x >> 4) * BTILE;

    // ---- stage: 16 weight rows x 2 slabs (4112 dwords = 1028 float4 each;
    // slab base obase*257 dwords is 16B-aligned since obase%16==0), plus
    // 8 x rows (512 float4). All loads fully coalesced.
    {
        const float4* gw = (const float4*)(wfreq  + obase * LDW);
        const float4* gg = (const float4*)(weight + obase * LDW);
        float4* lw4 = (float4*)lw;
        float4* lg4 = (float4*)lg;
#pragma unroll
        for (int k = 0; k < 4; ++k) {
            float4 v = gw[t + k * 256];
            v.x *= INV_2PI; v.y *= INV_2PI; v.z *= INV_2PI; v.w *= INV_2PI;
            lw4[t + k * 256] = v;
            lg4[t + k * 256] = gg[t + k * 256];
        }
        if (t < 4) {  // tail: 1028 - 1024
            float4 v = gw[1024 + t];
            v.x *= INV_2PI; v.y *= INV_2PI; v.z *= INV_2PI; v.w *= INV_2PI;
            lw4[1024 + t] = v;
            lg4[1024 + t] = gg[1024 + t];
        }
        const float4* gx = (const float4*)(x + b0 * IN_DIM);
        float4* lx4 = (float4*)lx;
        lx4[t]       = gx[t];
        lx4[t + 256] = gx[t + 256];
    }
    __syncthreads();

    const int rw = og * LDW;
    float acc[BTILE];
#pragma unroll
    for (int b = 0; b < BTILE; ++b) acc[b] = 0.f;

#pragma unroll
    for (int c = 0; c < 4; ++c) {
        const int i = c * 64 + iq * 4;
        // ds_read_b32 x8: bank = (og + 4*iq + j) % 32 -> exact 2-way, free
        const float w0 = lw[rw + i], w1 = lw[rw + i + 1],
                    w2 = lw[rw + i + 2], w3 = lw[rw + i + 3];
        const float g0 = lg[rw + i], g1 = lg[rw + i + 1],
                    g2 = lg[rw + i + 2], g3 = lg[rw + i + 3];
#pragma unroll
        for (int b = 0; b < BTILE; ++b) {
            const float4 xv = *(const float4*)&lx[b * IN_DIM + i];  // 16B aligned
            float a = acc[b];
            a = fmaf(g0, __builtin_amdgcn_sinf(w0 * xv.x), a);
            a = fmaf(g1, __builtin_amdgcn_sinf(w1 * xv.y), a);
            a = fmaf(g2, __builtin_amdgcn_sinf(w2 * xv.z), a);
            a = fmaf(g3, __builtin_amdgcn_sinf(w3 * xv.w), a);
            acc[b] = a;
        }
    }

    // bias column (x_ext = 1): add on one iq lane only. lw is pre-scaled.
    const float bias = lg[rw + IN_DIM] * __builtin_amdgcn_sinf(lw[rw + IN_DIM]);
    const float sel  = (iq == 0) ? bias : 0.f;
#pragma unroll
    for (int b = 0; b < BTILE; ++b) acc[b] += sel;

#pragma unroll
    for (int b = 0; b < BTILE; ++b) {
        float v = acc[b];
        v += __shfl_xor(v, 1);
        v += __shfl_xor(v, 2);
        v += __shfl_xor(v, 4);
        v += __shfl_xor(v, 8);
        acc[b] = v;
    }

    if (iq == 0) {
        const int o = obase + og;
#pragma unroll
        for (int b = 0; b < BTILE; ++b) {
            y[(b0 + b) * OUT_DIM + o] = acc[b];
        }
    }
}

extern "C" void kernel_launch(void* const* d_in, const int* in_sizes, int n_in,
                              void* d_out, int out_size, void* d_ws, size_t ws_size,
                              hipStream_t stream) {
    const float* x      = (const float*)d_in[0];
    const float* weight = (const float*)d_in[1];
    const float* wfreq  = (const float*)d_in[2];
    float* y            = (float*)d_out;

    const int B = in_sizes[0] / IN_DIM;               // 2048
    const int grid = (OUT_DIM / OTILE) * (B / BTILE); // 16 * 256 = 4096

    skan_kernel<<<grid, 256, 0, stream>>>(x, weight, wfreq, y);
}

// Round 4
// 75.627 us; speedup vs baseline: 1.0822x; 1.0822x over previous
//
#include <hip/hip_runtime.h>

// SKANLinear: y[b,o] = sum_{i=0}^{IN} weight[o,i] * sin(w[o,i] * x_ext[b,i])
// x_ext[b,IN] = 1.0. B=2048, IN=256, OUT=256. f32.
//
// R4 structure: lane = b (64 rows/block), wave = 2 wave-uniform o rows.
//  - weight/w come in via the SCALAR pipe (s_load; SGPR folds into VALU ops)
//  - x tile (64b x 64i) transposed through LDS (stride 65: 2-way = free),
//    pre-scaled by 1/(2pi) (v_sin_f32 takes revolutions), copied to regs
//  - inner loop: v_mul(s,v) + v_sin + v_fma(s,v,v) = 12 cyc/elem, NO memory
//  - each lane owns full (b,o) sums: zero reduction shuffles
// LDS 16.6KB -> 4 blocks/CU (16 waves/CU). Grid 32 b-tiles x 32 o-tiles.

#define IN_DIM 256
#define OUT_DIM 256
#define LDW 257
#define LXS 65            // LDS x-tile row stride (odd -> bank-friendly)
#define INV_2PI 0.15915494309189535f

__global__ __launch_bounds__(256, 4)
void skan_kernel(const float* __restrict__ x,      // [2048][256]
                 const float* __restrict__ weight, // [256][257]
                 const float* __restrict__ wfreq,  // [256][257]
                 float* __restrict__ y)            // [2048][256]
{
    __shared__ float lx[64 * LXS];   // x[b][i-chunk] * INV_2PI, transposed access

    const int t  = threadIdx.x;
    const int l  = t & 63;                                   // lane = local b
    const int wv = __builtin_amdgcn_readfirstlane(t >> 6);   // wave id, uniform

    const int obase = (blockIdx.x & 31) * 8;
    const int b0    = (blockIdx.x >> 5) * 64;

    const int o0 = obase + wv * 2;
    const int o1 = o0 + 1;
    const float* __restrict__ w0r = wfreq  + o0 * LDW;  // uniform -> s_load
    const float* __restrict__ g0r = weight + o0 * LDW;
    const float* __restrict__ w1r = wfreq  + o1 * LDW;
    const float* __restrict__ g1r = weight + o1 * LDW;

    // staging lane mapping: 16 rows per wave, 4 rows per instr, coalesced
    const int srow = wv * 16 + (l >> 4);   // +4k below
    const int scol = (l & 15) * 4;         // dword col within 64-wide chunk

    // bias column (i=256, x_ext=1): every lane owns a full (b,o) sum,
    // so every lane adds it exactly once -> init acc with it.
    float acc0 = g0r[IN_DIM] * __builtin_amdgcn_sinf(w0r[IN_DIM] * INV_2PI);
    float acc1 = g1r[IN_DIM] * __builtin_amdgcn_sinf(w1r[IN_DIM] * INV_2PI);

    // ---- prologue: stage chunk 0
    {
        const float* gx = x + b0 * IN_DIM;  // ic = 0
#pragma unroll
        for (int k = 0; k < 4; ++k) {
            const int r = srow + 4 * k;
            const float4 v = *(const float4*)(gx + r * IN_DIM + scol);
            float* d = &lx[r * LXS + scol];
            d[0] = v.x * INV_2PI; d[1] = v.y * INV_2PI;
            d[2] = v.z * INV_2PI; d[3] = v.w * INV_2PI;
        }
    }

    for (int ic = 0; ic < 4; ++ic) {
        __syncthreads();

        // copy my b-row's chunk to registers (ds_read, stride-65: 2-way free)
        float xs[64];
#pragma unroll
        for (int j = 0; j < 64; ++j) xs[j] = lx[l * LXS + j];

        __syncthreads();

        // stage next chunk while compute runs (regs double-buffer the tile)
        if (ic < 3) {
            const float* gx = x + b0 * IN_DIM + (ic + 1) * 64;
#pragma unroll
            for (int k = 0; k < 4; ++k) {
                const int r = srow + 4 * k;
                const float4 v = *(const float4*)(gx + r * IN_DIM + scol);
                float* d = &lx[r * LXS + scol];
                d[0] = v.x * INV_2PI; d[1] = v.y * INV_2PI;
                d[2] = v.z * INV_2PI; d[3] = v.w * INV_2PI;
            }
        }

        // inner: pure VALU. w/g are wave-uniform scalar loads (SGPR),
        // xs in VGPRs. 12 cyc per element per o.
        const int ib = ic * 64;
#pragma unroll
        for (int j = 0; j < 64; ++j) {
            const float xv = xs[j];
            acc0 = fmaf(g0r[ib + j], __builtin_amdgcn_sinf(w0r[ib + j] * xv), acc0);
            acc1 = fmaf(g1r[ib + j], __builtin_amdgcn_sinf(w1r[ib + j] * xv), acc1);
        }
    }

    // store: per-lane (b,o) result. 2 scatter stores per wave (64 rows).
    y[(b0 + l) * OUT_DIM + o0] = acc0;
    y[(b0 + l) * OUT_DIM + o1] = acc1;
}

extern "C" void kernel_launch(void* const* d_in, const int* in_sizes, int n_in,
                              void* d_out, int out_size, void* d_ws, size_t ws_size,
                              hipStream_t stream) {
    const float* x      = (const float*)d_in[0];
    const float* weight = (const float*)d_in[1];
    const float* wfreq  = (const float*)d_in[2];
    float* y            = (float*)d_out;

    const int B = in_sizes[0] / IN_DIM;            // 2048
    const int grid = (B / 64) * (OUT_DIM / 8);     // 32 * 32 = 1024

    skan_kernel<<<grid, 256, 0, stream>>>(x, weight, wfreq, y);
}